// Round 3
// baseline (1997.122 us; speedup 1.0000x reference)
//
#include <hip/hip_runtime.h>

constexpr int BATCH = 2048;
constexpr int SEQ   = 512;
constexpr int H     = 50;
constexpr int G4    = 200;   // 4*H gate rows
constexpr int NB    = 4;     // batch elements per block
constexpr int NT    = 512;   // threads per block (8 waves)
constexpr int HP    = 56;    // padded h length (14 float4s), split 28+28
constexpr int KH    = 28;    // k-half length

__device__ __forceinline__ float sigm(float x) {
    return 1.0f / (1.0f + __expf(-x));
}
__device__ __forceinline__ float tanh_fast(float x) {
    float a = __expf(-2.0f * fabsf(x));
    float t = (1.0f - a) / (1.0f + a);
    return copysignf(t, x);
}

__global__ __launch_bounds__(NT, 4) void lstm2_ksplit(
    const float* __restrict__ x,
    const float* __restrict__ Wih0, const float* __restrict__ Whh0,
    const float* __restrict__ bih0, const float* __restrict__ bhh0,
    const float* __restrict__ Wih1, const float* __restrict__ Whh1,
    const float* __restrict__ bih1, const float* __restrict__ bhh1,
    const float* __restrict__ fcW,  const float* __restrict__ fcb,
    float* __restrict__ out)
{
    __shared__ float sH0[NB * HP];   // layer0 h (padded, zeros beyond 49)
    __shared__ float sH2[NB * HP];   // layer1 h
    __shared__ float sG[NB * 256];   // gate preacts, [b][row]
    __shared__ float sX[NB * 64];    // staged x chunk (64 steps)

    const int t     = threadIdx.x;
    const int bbase = blockIdx.x * NB;

    for (int i = t; i < NB * HP; i += NT) { sH0[i] = 0.f; sH2[i] = 0.f; }

    // ---- matmul mapping: thread t<400 owns (row n, k-half kh) ----
    const bool mm   = (t < 2 * G4);
    const int  n    = t >> 1;
    const int  kh   = t & 1;
    const int  koff = kh * KH;

    // weights in registers: 28 floats per matrix (zeros in pad region)
    float w0[KH], wi1[KH], wh1[KH];
    #pragma unroll
    for (int i = 0; i < KH; ++i) { w0[i] = 0.f; wi1[i] = 0.f; wh1[i] = 0.f; }
    float wx0 = 0.f, bias0 = 0.f, bias1 = 0.f;
    if (mm) {
        #pragma unroll
        for (int i = 0; i < KH; ++i) {
            int k = koff + i;
            if (k < H) {
                w0 [i] = Whh0[n * H + k];
                wi1[i] = Wih1[n * H + k];
                wh1[i] = Whh1[n * H + k];
            }
        }
        if (kh == 0) {                       // only half 0 carries x-term/bias
            wx0   = Wih0[n];                 // INPUT_SIZE == 1
            bias0 = bih0[n] + bhh0[n];
            bias1 = bih1[n] + bhh1[n];
        }
    }

    // combine mapping (threads 0..199): (batch cb, hidden cj)
    const int cb = t / H;
    const int cj = t - cb * H;
    float c0 = 0.f, c1 = 0.f;

    __syncthreads();

    #pragma unroll 1
    for (int s = 0; s < SEQ; ++s) {
        // ---- stage next 64 timesteps of x (coalesced) ----
        if ((s & 63) == 0) {
            if (t < NB * 64)
                sX[t] = x[(bbase + (t >> 6)) * SEQ + s + (t & 63)];
            __syncthreads();
        }
        const int ss = s & 63;

        // ---- Phase A: layer0 gates: g = wx0*x_t + b0 + Whh0[n,koff:].h0 ----
        if (mm) {
            float acc[NB];
            #pragma unroll
            for (int b = 0; b < NB; ++b)
                acc[b] = fmaf(wx0, sX[b * 64 + ss], bias0);  // 0 for kh==1
            #pragma unroll
            for (int ic = 0; ic < KH / 4; ++ic) {
                #pragma unroll
                for (int b = 0; b < NB; ++b) {
                    float4 h = *(const float4*)&sH0[b * HP + koff + ic * 4];
                    acc[b] = fmaf(w0[ic * 4 + 0], h.x, acc[b]);
                    acc[b] = fmaf(w0[ic * 4 + 1], h.y, acc[b]);
                    acc[b] = fmaf(w0[ic * 4 + 2], h.z, acc[b]);
                    acc[b] = fmaf(w0[ic * 4 + 3], h.w, acc[b]);
                }
            }
            #pragma unroll
            for (int b = 0; b < NB; ++b) acc[b] += __shfl_xor(acc[b], 1);
            if (kh == 0) { sG[0 * 256 + n] = acc[0]; sG[1 * 256 + n] = acc[1]; }
            else         { sG[2 * 256 + n] = acc[2]; sG[3 * 256 + n] = acc[3]; }
        }
        __syncthreads();

        // ---- Phase B: layer0 combine -> c0 (regs), h0 -> LDS ----
        if (t < NB * H) {
            float gi = sG[cb * 256 +       cj];
            float gf = sG[cb * 256 +  50 + cj];
            float gg = sG[cb * 256 + 100 + cj];
            float go = sG[cb * 256 + 150 + cj];
            c0 = sigm(gf) * c0 + sigm(gi) * tanh_fast(gg);
            sH0[cb * HP + cj] = sigm(go) * tanh_fast(c0);
        }
        __syncthreads();

        // ---- Phase C: layer1 gates: g = b1 + Wih1.h1_t + Whh1.h2 ----
        if (mm) {
            float acc[NB];
            #pragma unroll
            for (int b = 0; b < NB; ++b) acc[b] = bias1;     // 0 for kh==1
            #pragma unroll
            for (int ic = 0; ic < KH / 4; ++ic) {
                #pragma unroll
                for (int b = 0; b < NB; ++b) {
                    float4 ha = *(const float4*)&sH0[b * HP + koff + ic * 4];
                    float4 hb = *(const float4*)&sH2[b * HP + koff + ic * 4];
                    acc[b] = fmaf(wi1[ic * 4 + 0], ha.x, acc[b]);
                    acc[b] = fmaf(wi1[ic * 4 + 1], ha.y, acc[b]);
                    acc[b] = fmaf(wi1[ic * 4 + 2], ha.z, acc[b]);
                    acc[b] = fmaf(wi1[ic * 4 + 3], ha.w, acc[b]);
                    acc[b] = fmaf(wh1[ic * 4 + 0], hb.x, acc[b]);
                    acc[b] = fmaf(wh1[ic * 4 + 1], hb.y, acc[b]);
                    acc[b] = fmaf(wh1[ic * 4 + 2], hb.z, acc[b]);
                    acc[b] = fmaf(wh1[ic * 4 + 3], hb.w, acc[b]);
                }
            }
            #pragma unroll
            for (int b = 0; b < NB; ++b) acc[b] += __shfl_xor(acc[b], 1);
            if (kh == 0) { sG[0 * 256 + n] = acc[0]; sG[1 * 256 + n] = acc[1]; }
            else         { sG[2 * 256 + n] = acc[2]; sG[3 * 256 + n] = acc[3]; }
        }
        __syncthreads();

        // ---- Phase D: layer1 combine -> c1 (regs), h2 -> LDS ----
        if (t < NB * H) {
            float gi = sG[cb * 256 +       cj];
            float gf = sG[cb * 256 +  50 + cj];
            float gg = sG[cb * 256 + 100 + cj];
            float go = sG[cb * 256 + 150 + cj];
            c1 = sigm(gf) * c1 + sigm(gi) * tanh_fast(gg);
            sH2[cb * HP + cj] = sigm(go) * tanh_fast(c1);
        }
        __syncthreads();
    }

    // ---- FC epilogue: out[b] = fcW . h2_last[b] + fcb ----
    if (t < NB * H) sG[cb * H + cj] = sH2[cb * HP + cj] * fcW[cj];
    __syncthreads();
    if (t < NB) {
        float sum = fcb[0];
        #pragma unroll
        for (int j = 0; j < H; ++j) sum += sG[t * H + j];
        out[bbase + t] = sum;
    }
}

extern "C" void kernel_launch(void* const* d_in, const int* in_sizes, int n_in,
                              void* d_out, int out_size, void* d_ws, size_t ws_size,
                              hipStream_t stream)
{
    const float* x    = (const float*)d_in[0];
    const float* Wih0 = (const float*)d_in[1];
    const float* Whh0 = (const float*)d_in[2];
    const float* bih0 = (const float*)d_in[3];
    const float* bhh0 = (const float*)d_in[4];
    const float* Wih1 = (const float*)d_in[5];
    const float* Whh1 = (const float*)d_in[6];
    const float* bih1 = (const float*)d_in[7];
    const float* bhh1 = (const float*)d_in[8];
    const float* fcW  = (const float*)d_in[9];
    const float* fcb  = (const float*)d_in[10];

    lstm2_ksplit<<<BATCH / NB, NT, 0, stream>>>(
        x, Wih0, Whh0, bih0, bhh0, Wih1, Whh1, bih1, bhh1, fcW, fcb,
        (float*)d_out);
}